// Round 19
// baseline (952.407 us; speedup 1.0000x reference)
//
#include <hip/hip_runtime.h>

// GraphSAGE: x(524288,256) -> FC relu -> 3x sage_conv -> out(8192,64)
// R19: MFMA operand swap (compute C^T-fragment) -> each lane stores 4
//      consecutive cols of one row: 16x u16x4 stores/thread instead of 64
//      scalar 2B stores (epilogue was VMEM-issue bound). Rest = R18.
constexpr int N0c = 524288, N1c = 262144, N2c = 65536, N3c = 8192;
constexpr int NTOT = N1c + N2c + N3c;            // 335872 (= 328*1024)

typedef __attribute__((ext_vector_type(8))) short   bf16x8;
typedef __attribute__((ext_vector_type(4))) float   f32x4;
typedef __attribute__((ext_vector_type(4))) unsigned short u16x4;
typedef __attribute__((ext_vector_type(8))) unsigned short u16x8;

__device__ inline unsigned short f2bf(float f) {
    union { float f; unsigned u; } v; v.f = f;
    unsigned r = v.u + 0x7FFF + ((v.u >> 16) & 1);   // RNE
    return (unsigned short)(r >> 16);
}
__device__ inline float bf2f(unsigned short u) {
    union { unsigned u; float f; } v; v.u = ((unsigned)u) << 16;
    return v.f;
}

__device__ inline void glds16(const void* g, void* l) {
    __builtin_amdgcn_global_load_lds(
        (const __attribute__((address_space(1))) unsigned int*)g,
        (__attribute__((address_space(3))) unsigned int*)l, 16, 0, 0);
}

// ---- weights -> bf16 transposed [N][K=256] + zero hist, one kernel ----
struct WPack { const float* w[7]; unsigned short* o[7]; };

__global__ __launch_bounds__(256)
void wconv_all(WPack p, int* __restrict__ hist)
{
    if (blockIdx.x >= 1408) {                       // zero hist: 328 blocks
        const int zid = (blockIdx.x - 1408) * 256 + threadIdx.x;
        ((int4*)hist)[zid] = make_int4(0, 0, 0, 0);
        return;
    }
    const int idx = blockIdx.x * 256 + threadIdx.x;   // 0 .. 360447
    int widx, off, N;
    if (idx < 327680) { widx = idx >> 16; off = idx & 65535; N = 256; }
    else {
        const int r = idx - 327680;
        widx = 5 + (r >> 14); off = r & 16383; N = 64;
        if (widx > 6) return;
    }
    const int k = off / N, n = off % N;
    p.o[widx][n * 256 + k] = f2bf(p.w[widx][off]);
}

__device__ inline bf16x8 pack_pair(const f32x4 u, const f32x4 v) {
    bf16x8 t;
    #pragma unroll
    for (int j = 0; j < 4; ++j) {
        t[j]     = (short)f2bf(u[j]);
        t[j + 4] = (short)f2bf(v[j]);
    }
    return t;
}

struct CsrArgs {
    const int* src0; const int* dst0;
    const int* src1; const int* dst1;
    const int* src2; const int* dst2;
    int e0, e01, etot;
};

// Fragment-order staging: granule r -> source addr of the 16B that
// (step s = r>>6, lane l = r&63) consumes. Step s = nt*SK + k0i;
// lane l: W row nt*16+(l&15), k-granule k0i*4+(l>>4).
template<int KC>
__device__ inline const unsigned short*
frag_src(const unsigned short* Wt, int r, int kh)
{
    constexpr int SK = KC / 32;
    const int s  = r >> 6;
    const int l  = r & 63;
    const int nt = s / SK;
    const int k0i = s % SK;
    const int n  = nt * 16 + (l & 15);
    const int kg = k0i * 4 + (l >> 4);
    return Wt + n * 256 + kh * KC + kg * 8;
}

// ---- unified GEMM body: 512 thr / 8 waves / 128 rows per block ----
// C[M x (NT*16)] = act(A1@Wt1^T (+A2@Wt2^T) + b).
// MFMA called as mfma(W_frag, x_frag, acc): D-tile holds, per lane,
// out-row = row0+(lane&15), out-cols nt*16 + kq*4 + rr  -> u16x4 stores.
template<int NT, int KC, bool DUAL, bool RELU, bool A_F32, bool OUT_BF16>
__device__ inline void gemm_body(const void* A1v, const void* A2v,
                                 const unsigned short* Wt1,
                                 const unsigned short* Wt2,
                                 const float* bias, void* Cv,
                                 unsigned short* Bs, int bid, int t)
{
    constexpr int N    = NT * 16;
    constexpr int PH   = 256 / KC;
    constexpr int SK   = KC / 32;
    constexpr int GPM  = 64 * NT * SK;               // granules per matrix/phase
    constexpr int TOTG = GPM * (DUAL ? 2 : 1);
    static_assert(TOTG % 512 == 0, "stage sizing");

    const int lane = t & 63;
    const int wv   = t >> 6;                 // 0..7
    const int col  = lane & 15;              // x-row-in-strip (B-operand col)
    const int kq   = lane >> 4;              // 0..3
    const long row0 = (long)bid * 128 + wv * 16;

    const unsigned short* A1h = (const unsigned short*)A1v;
    const float*          A1f = (const float*)A1v;
    const unsigned short* A2h = (const unsigned short*)A2v;

    f32x4 acc[NT];
    #pragma unroll
    for (int nt = 0; nt < NT; ++nt) acc[nt] = (f32x4){0.f, 0.f, 0.f, 0.f};

    const long ar = (row0 + col) * 256;

    // ping-pong register prefetch buffers (static indices after unroll)
    f32x4  fbuf[2][SK][2];
    bf16x8 h1buf[2][SK], h2buf[2][SK];

    auto issue_a = [&](int kh, int b) {
        #pragma unroll
        for (int q = 0; q < SK; ++q) {
            const long ac = ar + kh * KC + q * 32 + kq * 8;
            if constexpr (A_F32) {
                fbuf[b][q][0] = *(const f32x4*)&A1f[ac];
                fbuf[b][q][1] = *(const f32x4*)&A1f[ac + 4];
            } else {
                h1buf[b][q] = *(const bf16x8*)&A1h[ac];
                if constexpr (DUAL) h2buf[b][q] = *(const bf16x8*)&A2h[ac];
            }
        }
    };
    auto stage_w = [&](int kh) {
        #pragma unroll
        for (int it = 0; it < TOTG / 512; ++it) {
            const int g = it * 512 + t;
            const int m = DUAL ? (g / GPM) : 0;
            const int r = DUAL ? (g % GPM) : g;
            glds16(frag_src<KC>(m ? Wt2 : Wt1, r, kh),
                   &Bs[(it * 512 + wv * 64) * 8]);
        }
    };
    auto compute = [&](int b) {
        #pragma unroll
        for (int k0i = 0; k0i < SK; ++k0i) {
            bf16x8 a1, a2;
            if constexpr (A_F32) a1 = pack_pair(fbuf[b][k0i][0], fbuf[b][k0i][1]);
            else                 a1 = h1buf[b][k0i];
            if constexpr (DUAL)  a2 = h2buf[b][k0i];
            #pragma unroll
            for (int nt = 0; nt < NT; ++nt) {
                const bf16x8 b1 = *(const bf16x8*)&Bs[((nt * SK + k0i) * 64 + lane) * 8];
                acc[nt] = __builtin_amdgcn_mfma_f32_16x16x32_bf16(b1, a1, acc[nt], 0, 0, 0);
                if constexpr (DUAL) {
                    const bf16x8 b2 = *(const bf16x8*)&Bs[(GPM + (nt * SK + k0i) * 64 + lane) * 8];
                    acc[nt] = __builtin_amdgcn_mfma_f32_16x16x32_bf16(b2, a2, acc[nt], 0, 0, 0);
                }
            }
        }
    };

    issue_a(0, 0);
    stage_w(0);
    __syncthreads();               // vmcnt(0) drain: A in regs, W in LDS

    #pragma unroll
    for (int kh = 0; kh < PH; ++kh) {
        if (kh + 1 < PH) issue_a(kh + 1, (kh + 1) & 1);
        compute(kh & 1);
        if (kh + 1 < PH) {
            __syncthreads();
            stage_w(kh + 1);
            __syncthreads();
        }
    }

    // ---- epilogue: lane owns out-row row0+col, 4 consecutive cols per nt ----
    const long row = row0 + col;
    #pragma unroll
    for (int nt = 0; nt < NT; ++nt) {
        const int c0 = nt * 16 + kq * 4;
        const f32x4 bb = *(const f32x4*)&bias[c0];
        if constexpr (OUT_BF16) {
            u16x4 o;
            #pragma unroll
            for (int rr = 0; rr < 4; ++rr) {
                float v = acc[nt][rr] + bb[rr];
                if constexpr (RELU) v = fmaxf(v, 0.f);
                o[rr] = f2bf(v);
            }
            *(u16x4*)&((unsigned short*)Cv)[row * N + c0] = o;
        } else {
            f32x4 o;
            #pragma unroll
            for (int rr = 0; rr < 4; ++rr) {
                float v = acc[nt][rr] + bb[rr];
                if constexpr (RELU) v = fmaxf(v, 0.f);
                o[rr] = v;
            }
            *(f32x4*)&((float*)Cv)[row * N + c0] = o;
        }
    }
}

// fused: FC (blocks < gemmBlocks; KC=128, 64KB, PH=2) + rank pass
__global__ __launch_bounds__(512, 4)
void fc_rank_k(const float* __restrict__ A1f, const unsigned short* __restrict__ Wt1,
               const float* __restrict__ bias, unsigned short* __restrict__ Cv,
               CsrArgs a, int* __restrict__ hist, int* __restrict__ rank,
               int gemmBlocks)
{
    __shared__ unsigned short Bs[4096 * 8];          // 64 KB
    if ((int)blockIdx.x >= gemmBlocks) {
        const int i = ((int)blockIdx.x - gemmBlocks) * 512 + (int)threadIdx.x;
        if (i >= a.etot) return;
        const int* dstp; int e, hb;
        if (i < a.e0)       { dstp = a.dst0; e = i;         hb = 0; }
        else if (i < a.e01) { dstp = a.dst1; e = i - a.e0;  hb = N1c; }
        else                { dstp = a.dst2; e = i - a.e01; hb = N1c + N2c; }
        rank[i] = atomicAdd(&hist[hb + dstp[e]], 1);
        return;
    }
    gemm_body<16, 128, false, true, true, true>(
        A1f, nullptr, Wt1, nullptr, bias, Cv, Bs, (int)blockIdx.x, (int)threadIdx.x);
}

// dual GEMM: KC=64 per matrix (64KB/phase), PH=4
template<bool RELU, bool OUT_BF16>
__global__ __launch_bounds__(512, 4)
void gemm_dual_k(const void* __restrict__ A1v, const void* __restrict__ A2v,
                 const unsigned short* __restrict__ Wt1,
                 const unsigned short* __restrict__ Wt2,
                 const float* __restrict__ bias, void* __restrict__ Cv)
{
    __shared__ unsigned short Bs[4096 * 8];          // 64 KB
    gemm_body<16, 64, true, RELU, false, OUT_BF16>(
        A1v, A2v, Wt1, Wt2, bias, Cv, Bs, (int)blockIdx.x, (int)threadIdx.x);
}

// final layer: N=64 dual, KC=128 (32KB/phase), PH=2, f32 out
__global__ __launch_bounds__(512, 4)
void gemm_fin_k(const void* __restrict__ A1v, const void* __restrict__ A2v,
                const unsigned short* __restrict__ Wt1,
                const unsigned short* __restrict__ Wt2,
                const float* __restrict__ bias, void* __restrict__ Cv)
{
    __shared__ unsigned short Bs[2048 * 8];          // 32 KB
    gemm_body<4, 128, true, false, false, false>(
        A1v, A2v, Wt1, Wt2, bias, Cv, Bs, (int)blockIdx.x, (int)threadIdx.x);
}

__global__ __launch_bounds__(256)
void scan1_k(const int* __restrict__ hist, int* __restrict__ offs,
             int* __restrict__ bsum, int n)
{
    __shared__ int sm[256];
    const int t = threadIdx.x;
    const int base = blockIdx.x * 1024 + t * 4;
    int4 v = make_int4(0, 0, 0, 0);
    if (base < n) v = *(const int4*)&hist[base];
    const int s = v.x + v.y + v.z + v.w;
    int val = s;
    sm[t] = val; __syncthreads();
    #pragma unroll
    for (int off = 1; off < 256; off <<= 1) {
        const int add = (t >= off) ? sm[t - off] : 0;
        __syncthreads();
        val += add;
        sm[t] = val;
        __syncthreads();
    }
    const int excl = val - s;
    if (base < n) {
        offs[base]     = excl;
        offs[base + 1] = excl + v.x;
        offs[base + 2] = excl + v.x + v.y;
        offs[base + 3] = excl + v.x + v.y + v.z;
    }
    if (t == 255) bsum[blockIdx.x] = val;
}

__global__ __launch_bounds__(512)
void scan2_k(int* __restrict__ bsum, int nb)
{
    __shared__ int sm[512];
    const int t = threadIdx.x;
    const int s = (t < nb) ? bsum[t] : 0;
    int val = s;
    sm[t] = val; __syncthreads();
    #pragma unroll
    for (int off = 1; off < 512; off <<= 1) {
        const int add = (t >= off) ? sm[t - off] : 0;
        __syncthreads();
        val += add;
        sm[t] = val;
        __syncthreads();
    }
    if (t < nb) bsum[t] = val - s;
}

__global__ __launch_bounds__(256)
void scan3_k(int* __restrict__ offs, const int* __restrict__ bsum, int etot)
{
    const int i = blockIdx.x * 256 + threadIdx.x;
    offs[i] += bsum[i >> 10];
    if (i == 0) offs[NTOT] = etot;               // sentinel
}

// atomic-free placement using precomputed rank
__global__ __launch_bounds__(256)
void place_k(CsrArgs a, const int* __restrict__ offs, const int* __restrict__ rank,
             int* __restrict__ ssrc)
{
    const int i = blockIdx.x * 256 + threadIdx.x;
    if (i >= a.etot) return;
    const int* dstp; const int* srcp; int e, hb;
    if (i < a.e0)       { dstp = a.dst0; srcp = a.src0; e = i;         hb = 0; }
    else if (i < a.e01) { dstp = a.dst1; srcp = a.src1; e = i - a.e0;  hb = N1c; }
    else                { dstp = a.dst2; srcp = a.src2; e = i - a.e01; hb = N1c + N2c; }
    const int g = hb + dstp[e];
    ssrc[offs[g] + rank[i]] = srcp[e];
}

// one wave per dst row; half-wave covers a 512B row via u16x8.
// Exact 16-edge batches (no mask), then one masked 8- or 4-load tail batch.
__global__ __launch_bounds__(256)
void agg_k(const unsigned short* __restrict__ h, const int* __restrict__ ssrc,
           const int* __restrict__ ob, unsigned short* __restrict__ agg, int n)
{
    const int w    = blockIdx.x * 4 + (threadIdx.x >> 6);
    const int lane = threadIdx.x & 63;
    if (w >= n) return;
    const int beg = ob[w];
    const int end = ob[w + 1];
    const int hf  = lane >> 5;
    const int co  = (lane & 31) * 8;

    float acc[8] = {0.f, 0.f, 0.f, 0.f, 0.f, 0.f, 0.f, 0.f};

    int j = beg;
    for (; j + 16 <= end; j += 16) {             // exact batches: no masking
        u16x8 v[8];
        #pragma unroll
        for (int q = 0; q < 8; ++q)
            v[q] = *(const u16x8*)&h[(size_t)ssrc[j + 2 * q + hf] * 256 + co];
        #pragma unroll
        for (int q = 0; q < 8; ++q)
            #pragma unroll
            for (int c = 0; c < 8; ++c) acc[c] += bf2f(v[q][c]);
    }
    const int rem = end - j;
    if (rem > 8) {                               // masked 8-load batch
        u16x8 v[8]; bool ok[8];
        #pragma unroll
        for (int q = 0; q < 8; ++q) {
            const int e = j + 2 * q + hf;
            ok[q] = (e < end);
            v[q] = *(const u16x8*)&h[(size_t)ssrc[ok[q] ? e : (end - 1)] * 256 + co];
        }
        #pragma unroll
        for (int q = 0; q < 8; ++q)
            #pragma unroll
            for (int c = 0; c < 8; ++c) acc[c] += ok[q] ? bf2f(v[q][c]) : 0.0f;
    } else if (rem > 0) {                        // masked 4-load batch
        u16x8 v[4]; bool ok[4];
        #pragma unroll
        for (int q = 0; q < 4; ++q) {
            const int e = j + 2 * q + hf;
            ok[q] = (e < end);
            v[q] = *(const u16x8*)&h[(size_t)ssrc[ok[q] ? e : (end - 1)] * 256 + co];
        }
        #pragma unroll
        for (int q = 0; q < 4; ++q)
            #pragma unroll
            for (int c = 0; c < 8; ++c) acc[c] += ok[q] ? bf2f(v[q][c]) : 0.0f;
    }

    #pragma unroll
    for (int c = 0; c < 8; ++c) acc[c] += __shfl_xor(acc[c], 32);

    if (hf == 0) {
        const float inv = 1.0f / fmaxf((float)(end - beg), 1.0f);
        u16x8 o;
        #pragma unroll
        for (int c = 0; c < 8; ++c) o[c] = f2bf(acc[c] * inv);
        *(u16x8*)&agg[(size_t)w * 256 + co] = o;
    }
}

extern "C" void kernel_launch(void* const* d_in, const int* in_sizes, int n_in,
                              void* d_out, int out_size, void* d_ws, size_t ws_size,
                              hipStream_t stream)
{
    const float* x    = (const float*)d_in[0];
    const int*   src0 = (const int*)d_in[1];
    const int*   dst0 = (const int*)d_in[2];
    const int*   src1 = (const int*)d_in[3];
    const int*   dst1 = (const int*)d_in[4];
    const int*   src2 = (const int*)d_in[5];
    const int*   dst2 = (const int*)d_in[6];
    const float* Wfc  = (const float*)d_in[10];
    const float* bfc  = (const float*)d_in[11];
    const float* Ws0  = (const float*)d_in[12];
    const float* Wn0  = (const float*)d_in[13];
    const float* b0   = (const float*)d_in[14];
    const float* Ws1  = (const float*)d_in[15];
    const float* Wn1  = (const float*)d_in[16];
    const float* b1   = (const float*)d_in[17];
    const float* Ws2  = (const float*)d_in[18];
    const float* Wn2  = (const float*)d_in[19];
    const float* b2   = (const float*)d_in[20];
    const int E0 = in_sizes[1], E1 = in_sizes[3], E2 = in_sizes[5];
    const int Etot = E0 + E1 + E2;

    char* ws = (char*)d_ws;
    unsigned short* h0   = (unsigned short*)ws;                    // 256 MiB
    unsigned short* h1   = (unsigned short*)(ws + (256ULL << 20)); // 128 MiB
    unsigned short* h2   = (unsigned short*)(ws + (384ULL << 20)); //  32 MiB
    unsigned short* agg  = (unsigned short*)(ws + (416ULL << 20)); // 128 MiB
    unsigned short* Wt   = (unsigned short*)(ws + (544ULL << 20)); //   1 MiB
    int*            hist = (int*)(ws + (545ULL << 20));            // 1.31 MiB
    int*            offs = (int*)(ws + (547ULL << 20));            // 1.31 MiB +1
    int*            bsum = (int*)(ws + (549ULL << 20));            //   2 KiB
    int*            ssrc = (int*)(ws + (550ULL << 20));            // 12.9 MiB
    int*            rank = (int*)(ws + (564ULL << 20));            // 12.9 MiB

    unsigned short* wfc = Wt;
    unsigned short* ws0 = Wt + 65536;
    unsigned short* wn0 = Wt + 131072;
    unsigned short* ws1 = Wt + 196608;
    unsigned short* wn1 = Wt + 262144;
    unsigned short* ws2 = Wt + 327680;
    unsigned short* wn2 = Wt + 344064;

    const dim3 blk(256);

    // 1) weights -> bf16 [N][K] + zero hist (fused)
    WPack wp;
    wp.w[0] = Wfc; wp.w[1] = Ws0; wp.w[2] = Wn0; wp.w[3] = Ws1; wp.w[4] = Wn1;
    wp.w[5] = Ws2; wp.w[6] = Wn2;
    wp.o[0] = wfc; wp.o[1] = ws0; wp.o[2] = wn0; wp.o[3] = ws1; wp.o[4] = wn1;
    wp.o[5] = ws2; wp.o[6] = wn2;
    wconv_all<<<dim3(1408 + 328), blk, 0, stream>>>(wp, hist);

    // 2) fused: FC GEMM + rank atomic pass (overlapped)
    CsrArgs ca;
    ca.src0 = src0; ca.dst0 = dst0; ca.src1 = src1; ca.dst1 = dst1;
    ca.src2 = src2; ca.dst2 = dst2;
    ca.e0 = E0; ca.e01 = E0 + E1; ca.etot = Etot;
    const int gemmBlocks = N0c / 128;                     // 4096
    const int rankBlocks = (Etot + 511) / 512;
    fc_rank_k<<<dim3(gemmBlocks + rankBlocks), dim3(512), 0, stream>>>(
        x, wfc, bfc, h0, ca, hist, rank, gemmBlocks);

    // 3) scan + place
    scan1_k<<<dim3(NTOT / 1024), blk, 0, stream>>>(hist, offs, bsum, NTOT);
    scan2_k<<<dim3(1), dim3(512), 0, stream>>>(bsum, NTOT / 1024);
    scan3_k<<<dim3(NTOT / 256), blk, 0, stream>>>(offs, bsum, Etot);
    place_k<<<dim3((Etot + 255) / 256), blk, 0, stream>>>(ca, offs, rank, ssrc);

    // 4) layer 0
    agg_k<<<dim3(N1c / 4), blk, 0, stream>>>(h0, ssrc, offs, agg, N1c);
    gemm_dual_k<true, true><<<dim3(N1c / 128), dim3(512), 0, stream>>>(
        h0, agg, ws0, wn0, b0, h1);

    // 5) layer 1
    agg_k<<<dim3(N2c / 4), blk, 0, stream>>>(h1, ssrc, offs + N1c, agg, N2c);
    gemm_dual_k<true, true><<<dim3(N2c / 128), dim3(512), 0, stream>>>(
        h1, agg, ws1, wn1, b1, h2);

    // 6) layer 2
    agg_k<<<dim3(N3c / 4), blk, 0, stream>>>(h2, ssrc, offs + N1c + N2c, agg, N3c);
    gemm_fin_k<<<dim3(N3c / 128), dim3(512), 0, stream>>>(
        h2, agg, ws2, wn2, b2, (float*)d_out);
}

// Round 20
// 845.434 us; speedup vs baseline: 1.1265x; 1.1265x over previous
//
#include <hip/hip_runtime.h>

// GraphSAGE: x(524288,256) -> FC relu -> 3x sage_conv -> out(8192,64)
// R20 = R13 revert (best measured: 847.0 us). Fused FC+rank, single-atomic
//      CSR (rank/place), exact-batch gather agg, bf16 activations.
constexpr int N0c = 524288, N1c = 262144, N2c = 65536, N3c = 8192;
constexpr int NTOT = N1c + N2c + N3c;            // 335872 (= 328*1024)

typedef __attribute__((ext_vector_type(8))) short   bf16x8;
typedef __attribute__((ext_vector_type(4))) float   f32x4;
typedef __attribute__((ext_vector_type(8))) unsigned short u16x8;

__device__ inline unsigned short f2bf(float f) {
    union { float f; unsigned u; } v; v.f = f;
    unsigned r = v.u + 0x7FFF + ((v.u >> 16) & 1);   // RNE
    return (unsigned short)(r >> 16);
}
__device__ inline float bf2f(unsigned short u) {
    union { unsigned u; float f; } v; v.u = ((unsigned)u) << 16;
    return v.f;
}

__device__ inline void glds16(const void* g, void* l) {
    __builtin_amdgcn_global_load_lds(
        (const __attribute__((address_space(1))) unsigned int*)g,
        (__attribute__((address_space(3))) unsigned int*)l, 16, 0, 0);
}

// ---- weights -> bf16 transposed [N][K=256] + zero hist, one kernel ----
struct WPack { const float* w[7]; unsigned short* o[7]; };

__global__ __launch_bounds__(256)
void wconv_all(WPack p, int* __restrict__ hist)
{
    if (blockIdx.x >= 1408) {                       // zero hist: 328 blocks
        const int zid = (blockIdx.x - 1408) * 256 + threadIdx.x;
        ((int4*)hist)[zid] = make_int4(0, 0, 0, 0);
        return;
    }
    const int idx = blockIdx.x * 256 + threadIdx.x;   // 0 .. 360447
    int widx, off, N;
    if (idx < 327680) { widx = idx >> 16; off = idx & 65535; N = 256; }
    else {
        const int r = idx - 327680;
        widx = 5 + (r >> 14); off = r & 16383; N = 64;
        if (widx > 6) return;
    }
    const int k = off / N, n = off % N;
    p.o[widx][n * 256 + k] = f2bf(p.w[widx][off]);
}

__device__ inline bf16x8 pack_bf8(const float* p) {
    const f32x4 u = *(const f32x4*)p;
    const f32x4 v = *(const f32x4*)(p + 4);
    bf16x8 t;
    #pragma unroll
    for (int j = 0; j < 4; ++j) {
        t[j]     = (short)f2bf(u[j]);
        t[j + 4] = (short)f2bf(v[j]);
    }
    return t;
}

struct CsrArgs {
    const int* src0; const int* dst0;
    const int* src1; const int* dst1;
    const int* src2; const int* dst2;
    int e0, e01, etot;
};

// ---- fused: FC GEMM (blocks < gemmBlocks) + rank pass (blocks >= gemmBlocks) ----
// FC: C[M x 256] = relu( A(f32) @ Wt^T + b ), KC=128, 2 phases, 512 thr/8 waves.
__global__ __launch_bounds__(512, 2)
void fc_rank_k(const float* __restrict__ A1f, const unsigned short* __restrict__ Wt1,
               const float* __restrict__ bias, unsigned short* __restrict__ Cv,
               CsrArgs a, int* __restrict__ hist, int* __restrict__ rank,
               int gemmBlocks)
{
    if ((int)blockIdx.x >= gemmBlocks) {
        // ---- rank: one atomic pass builds hist + per-edge rank ----
        const int i = ((int)blockIdx.x - gemmBlocks) * 512 + (int)threadIdx.x;
        if (i >= a.etot) return;
        const int* dstp; int e, hb;
        if (i < a.e0)       { dstp = a.dst0; e = i;         hb = 0; }
        else if (i < a.e01) { dstp = a.dst1; e = i - a.e0;  hb = N1c; }
        else                { dstp = a.dst2; e = i - a.e01; hb = N1c + N2c; }
        rank[i] = atomicAdd(&hist[hb + dstp[e]], 1);
        return;
    }

    constexpr int KC = 128, SLOTS = KC / 8, GPM = 256 * SLOTS;   // 4096 granules
    __shared__ unsigned short Bs[GPM * 8];

    const int t    = threadIdx.x;
    const int lane = t & 63;
    const int wv   = t >> 6;
    const int col  = lane & 15;
    const int kg   = lane >> 4;
    const int swz  = (col & 7) << 3;
    const long row0 = (long)blockIdx.x * 128 + wv * 16;

    f32x4 acc[16];
    #pragma unroll
    for (int nt = 0; nt < 16; ++nt) acc[nt] = (f32x4){0.f, 0.f, 0.f, 0.f};

    const long ar = (row0 + col) * 256;

    for (int kh = 0; kh < 2; ++kh) {
        if (kh) __syncthreads();
        #pragma unroll
        for (int it = 0; it < GPM / 512; ++it) {
            const int g  = it * 512 + t;
            const int n  = g / SLOTS;
            const int s  = g % SLOTS;
            const int ss = s ^ (n & 7);
            glds16(Wt1 + n * 256 + kh * KC + ss * 8, &Bs[(it * 512 + wv * 64) * 8]);
        }
        __syncthreads();

        #pragma unroll
        for (int k0 = 0; k0 < KC; k0 += 32) {
            const int kx = (k0 + kg * 8) ^ swz;
            const bf16x8 a1 = pack_bf8(&A1f[ar + kh * KC + k0 + kg * 8]);
            #pragma unroll
            for (int nt = 0; nt < 16; ++nt) {
                const bf16x8 b1 = *(const bf16x8*)&Bs[(nt * 16 + col) * KC + kx];
                acc[nt] = __builtin_amdgcn_mfma_f32_16x16x32_bf16(a1, b1, acc[nt], 0, 0, 0);
            }
        }
    }

    #pragma unroll
    for (int nt = 0; nt < 16; ++nt) {
        const int c = nt * 16 + col;
        const float bb = bias[c];
        #pragma unroll
        for (int rr = 0; rr < 4; ++rr) {
            const long row = row0 + kg * 4 + rr;
            Cv[row * 256 + c] = f2bf(fmaxf(acc[nt][rr] + bb, 0.f));
        }
    }
}

// C[M x N] = act( A1 @ Wt1^T (+ A2 @ Wt2^T) + b ), K=256, N=NT*16.
template<int NT, int KC, bool DUAL, bool RELU, bool A_F32, bool OUT_BF16>
__global__ __launch_bounds__(512, 2)
void gemm2(const void* __restrict__ A1v, const void* __restrict__ A2v,
           const unsigned short* __restrict__ Wt1,
           const unsigned short* __restrict__ Wt2,
           const float* __restrict__ bias, void* __restrict__ Cv)
{
    constexpr int N     = NT * 16;
    constexpr int PH    = 256 / KC;
    constexpr int SLOTS = KC / 8;
    constexpr int GPM   = N * SLOTS;
    constexpr int TOTG  = GPM * (DUAL ? 2 : 1);
    static_assert(TOTG == 4096, "LDS sizing");
    __shared__ unsigned short Bs[TOTG * 8];

    const int t    = threadIdx.x;
    const int lane = t & 63;
    const int wv   = t >> 6;
    const int col  = lane & 15;
    const int kg   = lane >> 4;
    const int swz  = (col & 7) << 3;
    const long row0 = (long)blockIdx.x * 128 + wv * 16;

    const unsigned short* A1h = (const unsigned short*)A1v;
    const float*          A1f = (const float*)A1v;
    const unsigned short* A2h = (const unsigned short*)A2v;

    f32x4 acc[NT];
    #pragma unroll
    for (int nt = 0; nt < NT; ++nt) acc[nt] = (f32x4){0.f, 0.f, 0.f, 0.f};

    const long ar = (row0 + col) * 256;

    for (int kh = 0; kh < PH; ++kh) {
        if (kh) __syncthreads();
        #pragma unroll
        for (int it = 0; it < TOTG / 512; ++it) {
            const int g  = it * 512 + t;
            const int m  = DUAL ? (g / GPM) : 0;
            const int gm = DUAL ? (g % GPM) : g;
            const int n  = gm / SLOTS;
            const int s  = gm % SLOTS;
            const int ss = s ^ (n & 7);
            const unsigned short* srcb =
                (m ? Wt2 : Wt1) + n * 256 + kh * KC + ss * 8;
            glds16(srcb, &Bs[(it * 512 + wv * 64) * 8]);
        }
        __syncthreads();

        #pragma unroll
        for (int k0 = 0; k0 < KC; k0 += 32) {
            const int kx = (k0 + kg * 8) ^ swz;
            const long ac = ar + kh * KC + k0 + kg * 8;
            bf16x8 a1, a2;
            if constexpr (A_F32) a1 = pack_bf8(&A1f[ac]);
            else                 a1 = *(const bf16x8*)&A1h[ac];
            if constexpr (DUAL)  a2 = *(const bf16x8*)&A2h[ac];
            #pragma unroll
            for (int nt = 0; nt < NT; ++nt) {
                const bf16x8 b1 = *(const bf16x8*)&Bs[(nt * 16 + col) * KC + kx];
                acc[nt] = __builtin_amdgcn_mfma_f32_16x16x32_bf16(a1, b1, acc[nt], 0, 0, 0);
                if constexpr (DUAL) {
                    const bf16x8 b2 = *(const bf16x8*)&Bs[GPM * 8 + (nt * 16 + col) * KC + kx];
                    acc[nt] = __builtin_amdgcn_mfma_f32_16x16x32_bf16(a2, b2, acc[nt], 0, 0, 0);
                }
            }
        }
    }

    #pragma unroll
    for (int nt = 0; nt < NT; ++nt) {
        const int c = nt * 16 + col;
        const float bb = bias[c];
        #pragma unroll
        for (int rr = 0; rr < 4; ++rr) {
            const long row = row0 + kg * 4 + rr;
            float o = acc[nt][rr] + bb;
            if constexpr (RELU) o = fmaxf(o, 0.f);
            if constexpr (OUT_BF16)
                ((unsigned short*)Cv)[row * N + c] = f2bf(o);
            else
                ((float*)Cv)[row * N + c] = o;
        }
    }
}

__global__ __launch_bounds__(256)
void scan1_k(const int* __restrict__ hist, int* __restrict__ offs,
             int* __restrict__ bsum, int n)
{
    __shared__ int sm[256];
    const int t = threadIdx.x;
    const int base = blockIdx.x * 1024 + t * 4;
    int4 v = make_int4(0, 0, 0, 0);
    if (base < n) v = *(const int4*)&hist[base];
    const int s = v.x + v.y + v.z + v.w;
    int val = s;
    sm[t] = val; __syncthreads();
    #pragma unroll
    for (int off = 1; off < 256; off <<= 1) {
        const int add = (t >= off) ? sm[t - off] : 0;
        __syncthreads();
        val += add;
        sm[t] = val;
        __syncthreads();
    }
    const int excl = val - s;
    if (base < n) {
        offs[base]     = excl;
        offs[base + 1] = excl + v.x;
        offs[base + 2] = excl + v.x + v.y;
        offs[base + 3] = excl + v.x + v.y + v.z;
    }
    if (t == 255) bsum[blockIdx.x] = val;
}

__global__ __launch_bounds__(512)
void scan2_k(int* __restrict__ bsum, int nb)
{
    __shared__ int sm[512];
    const int t = threadIdx.x;
    const int s = (t < nb) ? bsum[t] : 0;
    int val = s;
    sm[t] = val; __syncthreads();
    #pragma unroll
    for (int off = 1; off < 512; off <<= 1) {
        const int add = (t >= off) ? sm[t - off] : 0;
        __syncthreads();
        val += add;
        sm[t] = val;
        __syncthreads();
    }
    if (t < nb) bsum[t] = val - s;
}

__global__ __launch_bounds__(256)
void scan3_k(int* __restrict__ offs, const int* __restrict__ bsum, int etot)
{
    const int i = blockIdx.x * 256 + threadIdx.x;
    offs[i] += bsum[i >> 10];
    if (i == 0) offs[NTOT] = etot;               // sentinel
}

// atomic-free placement using precomputed rank
__global__ __launch_bounds__(256)
void place_k(CsrArgs a, const int* __restrict__ offs, const int* __restrict__ rank,
             int* __restrict__ ssrc)
{
    const int i = blockIdx.x * 256 + threadIdx.x;
    if (i >= a.etot) return;
    const int* dstp; const int* srcp; int e, hb;
    if (i < a.e0)       { dstp = a.dst0; srcp = a.src0; e = i;         hb = 0; }
    else if (i < a.e01) { dstp = a.dst1; srcp = a.src1; e = i - a.e0;  hb = N1c; }
    else                { dstp = a.dst2; srcp = a.src2; e = i - a.e01; hb = N1c + N2c; }
    const int g = hb + dstp[e];
    ssrc[offs[g] + rank[i]] = srcp[e];
}

// one wave per dst row; half-wave covers a 512B row via u16x8.
// Exact 16-edge batches (no mask), then one masked 8- or 4-load tail batch.
__global__ __launch_bounds__(256)
void agg_k(const unsigned short* __restrict__ h, const int* __restrict__ ssrc,
           const int* __restrict__ ob, unsigned short* __restrict__ agg, int n)
{
    const int w    = blockIdx.x * 4 + (threadIdx.x >> 6);
    const int lane = threadIdx.x & 63;
    if (w >= n) return;
    const int beg = ob[w];
    const int end = ob[w + 1];
    const int hf  = lane >> 5;
    const int co  = (lane & 31) * 8;

    float acc[8] = {0.f, 0.f, 0.f, 0.f, 0.f, 0.f, 0.f, 0.f};

    int j = beg;
    for (; j + 16 <= end; j += 16) {             // exact batches: no masking
        u16x8 v[8];
        #pragma unroll
        for (int q = 0; q < 8; ++q)
            v[q] = *(const u16x8*)&h[(size_t)ssrc[j + 2 * q + hf] * 256 + co];
        #pragma unroll
        for (int q = 0; q < 8; ++q)
            #pragma unroll
            for (int c = 0; c < 8; ++c) acc[c] += bf2f(v[q][c]);
    }
    const int rem = end - j;
    if (rem > 8) {                               // masked 8-load batch
        u16x8 v[8]; bool ok[8];
        #pragma unroll
        for (int q = 0; q < 8; ++q) {
            const int e = j + 2 * q + hf;
            ok[q] = (e < end);
            v[q] = *(const u16x8*)&h[(size_t)ssrc[ok[q] ? e : (end - 1)] * 256 + co];
        }
        #pragma unroll
        for (int q = 0; q < 8; ++q)
            #pragma unroll
            for (int c = 0; c < 8; ++c) acc[c] += ok[q] ? bf2f(v[q][c]) : 0.0f;
    } else if (rem > 0) {                        // masked 4-load batch
        u16x8 v[4]; bool ok[4];
        #pragma unroll
        for (int q = 0; q < 4; ++q) {
            const int e = j + 2 * q + hf;
            ok[q] = (e < end);
            v[q] = *(const u16x8*)&h[(size_t)ssrc[ok[q] ? e : (end - 1)] * 256 + co];
        }
        #pragma unroll
        for (int q = 0; q < 4; ++q)
            #pragma unroll
            for (int c = 0; c < 8; ++c) acc[c] += ok[q] ? bf2f(v[q][c]) : 0.0f;
    }

    #pragma unroll
    for (int c = 0; c < 8; ++c) acc[c] += __shfl_xor(acc[c], 32);

    if (hf == 0) {
        const float inv = 1.0f / fmaxf((float)(end - beg), 1.0f);
        u16x8 o;
        #pragma unroll
        for (int c = 0; c < 8; ++c) o[c] = f2bf(acc[c] * inv);
        *(u16x8*)&agg[(size_t)w * 256 + co] = o;
    }
}

extern "C" void kernel_launch(void* const* d_in, const int* in_sizes, int n_in,
                              void* d_out, int out_size, void* d_ws, size_t ws_size,
                              hipStream_t stream)
{
    const float* x    = (const float*)d_in[0];
    const int*   src0 = (const int*)d_in[1];
    const int*   dst0 = (const int*)d_in[2];
    const int*   src1 = (const int*)d_in[3];
    const int*   dst1 = (const int*)d_in[4];
    const int*   src2 = (const int*)d_in[5];
    const int*   dst2 = (const int*)d_in[6];
    const float* Wfc  = (const float*)d_in[10];
    const float* bfc  = (const float*)d_in[11];
    const float* Ws0  = (const float*)d_in[12];
    const float* Wn0  = (const float*)d_in[13];
    const float* b0   = (const float*)d_in[14];
    const float* Ws1  = (const float*)d_in[15];
    const float* Wn1  = (const float*)d_in[16];
    const float* b1   = (const float*)d_in[17];
    const float* Ws2  = (const float*)d_in[18];
    const float* Wn2  = (const float*)d_in[19];
    const float* b2   = (const float*)d_in[20];
    const int E0 = in_sizes[1], E1 = in_sizes[3], E2 = in_sizes[5];
    const int Etot = E0 + E1 + E2;

    char* ws = (char*)d_ws;
    unsigned short* h0   = (unsigned short*)ws;                    // 256 MiB
    unsigned short* h1   = (unsigned short*)(ws + (256ULL << 20)); // 128 MiB
    unsigned short* h2   = (unsigned short*)(ws + (384ULL << 20)); //  32 MiB
    unsigned short* agg  = (unsigned short*)(ws + (416ULL << 20)); // 128 MiB
    unsigned short* Wt   = (unsigned short*)(ws + (544ULL << 20)); //   1 MiB
    int*            hist = (int*)(ws + (545ULL << 20));            // 1.31 MiB
    int*            offs = (int*)(ws + (547ULL << 20));            // 1.31 MiB +1
    int*            bsum = (int*)(ws + (549ULL << 20));            //   2 KiB
    int*            ssrc = (int*)(ws + (550ULL << 20));            // 12.9 MiB
    int*            rank = (int*)(ws + (564ULL << 20));            // 12.9 MiB

    unsigned short* wfc = Wt;
    unsigned short* ws0 = Wt + 65536;
    unsigned short* wn0 = Wt + 131072;
    unsigned short* ws1 = Wt + 196608;
    unsigned short* wn1 = Wt + 262144;
    unsigned short* ws2 = Wt + 327680;
    unsigned short* wn2 = Wt + 344064;

    const dim3 blk(256);

    // 1) weights -> bf16 [N][K] + zero hist (fused)
    WPack wp;
    wp.w[0] = Wfc; wp.w[1] = Ws0; wp.w[2] = Wn0; wp.w[3] = Ws1; wp.w[4] = Wn1;
    wp.w[5] = Ws2; wp.w[6] = Wn2;
    wp.o[0] = wfc; wp.o[1] = ws0; wp.o[2] = wn0; wp.o[3] = ws1; wp.o[4] = wn1;
    wp.o[5] = ws2; wp.o[6] = wn2;
    wconv_all<<<dim3(1408 + 328), blk, 0, stream>>>(wp, hist);

    // 2) fused: FC GEMM + rank atomic pass (overlapped)
    CsrArgs ca;
    ca.src0 = src0; ca.dst0 = dst0; ca.src1 = src1; ca.dst1 = dst1;
    ca.src2 = src2; ca.dst2 = dst2;
    ca.e0 = E0; ca.e01 = E0 + E1; ca.etot = Etot;
    const int gemmBlocks = N0c / 128;                     // 4096
    const int rankBlocks = (Etot + 511) / 512;
    fc_rank_k<<<dim3(gemmBlocks + rankBlocks), dim3(512), 0, stream>>>(
        x, wfc, bfc, h0, ca, hist, rank, gemmBlocks);

    // 3) scan + place
    scan1_k<<<dim3(NTOT / 1024), blk, 0, stream>>>(hist, offs, bsum, NTOT);
    scan2_k<<<dim3(1), dim3(512), 0, stream>>>(bsum, NTOT / 1024);
    scan3_k<<<dim3(NTOT / 256), blk, 0, stream>>>(offs, bsum, Etot);
    place_k<<<dim3((Etot + 255) / 256), blk, 0, stream>>>(ca, offs, rank, ssrc);

    // 4) layer 0
    agg_k<<<dim3(N1c / 4), blk, 0, stream>>>(h0, ssrc, offs, agg, N1c);
    gemm2<16, 64, true, true, false, true><<<dim3(N1c / 128), dim3(512), 0, stream>>>(
        h0, agg, ws0, wn0, b0, h1);

    // 5) layer 1
    agg_k<<<dim3(N2c / 4), blk, 0, stream>>>(h1, ssrc, offs + N1c, agg, N2c);
    gemm2<16, 64, true, true, false, true><<<dim3(N2c / 128), dim3(512), 0, stream>>>(
        h1, agg, ws1, wn1, b1, h2);

    // 6) layer 2
    agg_k<<<dim3(N3c / 4), blk, 0, stream>>>(h2, ssrc, offs + N1c + N2c, agg, N3c);
    gemm2<4, 256, true, false, false, false><<<dim3(N3c / 128), dim3(512), 0, stream>>>(
        h2, agg, ws2, wn2, b2, (float*)d_out);
}